// Round 10
// baseline (47.090 us; speedup 1.0000x reference)
//
#include <hip/hip_runtime.h>
#include <hip/hip_bf16.h>
#include <stdint.h>

#define N 8192
#define D 256                          // fp8 row = 256 bytes
#define RPB 512                        // rows per simlse block (8 waves x 64)
#define CPB 256                        // cols per simlse block (64 KB LDS panel)
#define COLG (N / CPB)                 // 32
#define CTILE 32
#define NT (CPB / CTILE)               // 8 tiles, no sync between them
#define E_CONST 2.71828182845904523536f

typedef __attribute__((ext_vector_type(4))) int i32x4;
typedef __attribute__((ext_vector_type(8))) int i32x8;
typedef __attribute__((ext_vector_type(16))) float f32x16;

typedef const __attribute__((address_space(1))) void gvoid_t;
typedef __attribute__((address_space(3))) void lvoid_t;
__device__ inline void gload_lds16(const void* g, void* l) {
  __builtin_amdgcn_global_load_lds((gvoid_t*)g, (lvoid_t*)l, 16, 0, 0);
}

// fp32 -> e4m3fn (RNE), manual fallback if builtin missing
#if !__has_builtin(__builtin_amdgcn_cvt_pk_fp8_f32)
__device__ inline unsigned int f2e4m3(float x) {
  union { float f; unsigned u; } c; c.f = x;
  unsigned s = (c.u >> 31) << 7;
  float ax = fabsf(x);
  if (!(ax > 0.0f)) return s;
  if (ax >= 448.0f) return s | 0x7E;
  int e; float m = frexpf(ax, &e);
  int E = e - 1 + 7;
  if (E <= 0) {
    int qi = (int)rintf(ax * 512.0f);
    if (qi > 7) return s | 0x08;
    return s | (unsigned)qi;
  }
  int qi = (int)rintf(m * 16.0f);
  if (qi == 16) { qi = 8; E += 1; }
  if (E > 15) return s | 0x7E;
  return s | (unsigned)((E << 3) | (qi - 8));
}
#endif

// ---- kernel 1: normalize fp32->fp8 + positive-pair dot + out zero-init ----
// Block b: rows {2b, 2b+1, 2b+4096, 2b+4097}; pos[i]=pos[i+4096]=dot pair.
__global__ __launch_bounds__(256) void norm_kernel(const float* __restrict__ feat,
                                                   unsigned char* __restrict__ f8,
                                                   float* __restrict__ pos,
                                                   float* __restrict__ out) {
  __shared__ float4 sh[4][64];
  int wave = threadIdx.x >> 6, lane = threadIdx.x & 63;
  int base = blockIdx.x << 1;
  int row = (wave < 2) ? (base + wave) : (4096 + base + (wave - 2));
  const float4 v = *(const float4*)(feat + (size_t)row * D + lane * 4);
  float ss = v.x * v.x + v.y * v.y + v.z * v.z + v.w * v.w;
  for (int m = 1; m < 64; m <<= 1) ss += __shfl_xor(ss, m, 64);
  float rn = 1.0f / fmaxf(sqrtf(ss), 1e-12f);
  float4 nv = make_float4(v.x * rn, v.y * rn, v.z * rn, v.w * rn);
#if __has_builtin(__builtin_amdgcn_cvt_pk_fp8_f32)
  int p = __builtin_amdgcn_cvt_pk_fp8_f32(nv.x, nv.y, 0, 0);
  p = __builtin_amdgcn_cvt_pk_fp8_f32(nv.z, nv.w, p, 1);
#else
  int p = (int)(f2e4m3(nv.x) | (f2e4m3(nv.y) << 8) |
                (f2e4m3(nv.z) << 16) | (f2e4m3(nv.w) << 24));
#endif
  *(int*)(f8 + (size_t)row * D + lane * 4) = p;
  sh[wave][lane] = nv;
  __syncthreads();
  if (wave < 2) {
    float4 q = sh[wave + 2][lane];
    float d = nv.x * q.x + nv.y * q.y + nv.z * q.z + nv.w * q.w;
    for (int m = 1; m < 64; m <<= 1) d += __shfl_xor(d, m, 64);
    if (lane == 0) {
      pos[base + wave] = d;
      pos[4096 + base + wave] = d;
    }
  }
  if (blockIdx.x == 0 && threadIdx.x == 0) out[0] = 0.0f;
}

// ---- kernel 2: fp8 sim + sum(exp(sim)); whole B panel staged ONCE ----
// 8 waves x 64 rows = 512 rows/block; 256-col panel in 64 KB LDS; single
// vmcnt(0)+barrier, then 8 tiles of pure ds_read->MFMA->exp (no sync).
__global__ __launch_bounds__(512, 2) void simlse_kernel(const unsigned char* __restrict__ f8,
                                                        float* __restrict__ slab) {
  __shared__ char lds[CPB * D];   // 64 KB
  const char* fb = (const char*)f8;
  int tid = threadIdx.x;
  int wave = tid >> 6, lane = tid & 63;
  int c31 = lane & 31, h = lane >> 5;
  int pi = blockIdx.x >> 5;   // 0..15 row panel
  int cg = blockIdx.x & 31;   // 0..31 col group
  int rowbase = pi * RPB + wave * 64;
  int colbase = cg * CPB;

  // A fragments: 2 m-tiles x 4 K-chunks (64 rows/wave), 64 VGPRs
  i32x8 a[2][4];
#pragma unroll
  for (int mt = 0; mt < 2; ++mt) {
    const char* ar = fb + (size_t)(rowbase + mt * 32 + c31) * D + h * 32;
#pragma unroll
    for (int m = 0; m < 4; ++m) {
      i32x4 lo = *(const i32x4*)(ar + m * 64);
      i32x4 hi = *(const i32x4*)(ar + m * 64 + 16);
      a[mt][m] = __builtin_shufflevector(lo, hi, 0, 1, 2, 3, 4, 5, 6, 7);
    }
  }

  // stage the whole 64 KB B panel: 4096 chunks of 16 B, 8 per thread
#pragma unroll
  for (int i = 0; i < 8; ++i) {
    int cbase = i * 512 + wave * 64;            // wave-uniform chunk base
    int c = cbase + lane;
    int r = c >> 4;                             // panel col-row 0..255
    int g = ((c & 15) * 16) ^ ((r & 7) << 4);   // pre-swizzled source byte
    gload_lds16(fb + (size_t)(colbase + r) * D + g, lds + cbase * 16);
  }
  asm volatile("s_waitcnt vmcnt(0)" ::: "memory");
  __builtin_amdgcn_s_barrier();
  __builtin_amdgcn_sched_barrier(0);

#pragma unroll
  for (int mt = 0; mt < 2; ++mt)
#pragma unroll
    for (int m = 0; m < 4; ++m)
      asm volatile("" : "+v"(a[mt][m]));   // pin fragments in registers

  float s0[16], s1[16];
#pragma unroll
  for (int r = 0; r < 16; ++r) { s0[r] = 0.0f; s1[r] = 0.0f; }

  int swz = (c31 & 7) << 4;
  for (int ct = 0; ct < NT; ++ct) {
    const char* bc = lds + (ct * 32 + c31) * 256;
    f32x16 acc0 = {0,0,0,0,0,0,0,0,0,0,0,0,0,0,0,0};
    f32x16 acc1 = {0,0,0,0,0,0,0,0,0,0,0,0,0,0,0,0};
#pragma unroll
    for (int m = 0; m < 4; ++m) {
      int kb = m * 64 + h * 32;
      i32x4 lo = *(const i32x4*)(bc + (kb ^ swz));
      i32x4 hi = *(const i32x4*)(bc + ((kb + 16) ^ swz));
      i32x8 bv = __builtin_shufflevector(lo, hi, 0, 1, 2, 3, 4, 5, 6, 7);
      acc0 = __builtin_amdgcn_mfma_scale_f32_32x32x64_f8f6f4(
          a[0][m], bv, acc0, 0, 0, 0, 127, 0, 127);
      acc1 = __builtin_amdgcn_mfma_scale_f32_32x32x64_f8f6f4(
          a[1][m], bv, acc1, 0, 0, 0, 127, 0, 127);
    }
#pragma unroll
    for (int r = 0; r < 16; ++r) {
      s0[r] += __expf(acc0[r]);
      s1[r] += __expf(acc1[r]);
    }
  }

  // reduce each row-sum across the 32 col-lanes
#pragma unroll
  for (int r = 0; r < 16; ++r) {
    s0[r] += __shfl_xor(s0[r], 1, 64);  s1[r] += __shfl_xor(s1[r], 1, 64);
    s0[r] += __shfl_xor(s0[r], 2, 64);  s1[r] += __shfl_xor(s1[r], 2, 64);
    s0[r] += __shfl_xor(s0[r], 4, 64);  s1[r] += __shfl_xor(s1[r], 4, 64);
    s0[r] += __shfl_xor(s0[r], 8, 64);  s1[r] += __shfl_xor(s1[r], 8, 64);
    s0[r] += __shfl_xor(s0[r], 16, 64); s1[r] += __shfl_xor(s1[r], 16, 64);
  }
  if (c31 == 0) {
#pragma unroll
    for (int r = 0; r < 16; ++r) {
      int rr = (r & 3) + 8 * (r >> 2) + 4 * h;     // C/D row mapping
      slab[(size_t)cg * N + rowbase + rr]      = s0[r];
      slab[(size_t)cg * N + rowbase + 32 + rr] = s1[r];
    }
  }
}

// ---- kernel 3: combine slab -> scalar loss ----
__global__ __launch_bounds__(256) void final_kernel(const float* __restrict__ slab,
                                                    const float* __restrict__ pos,
                                                    float* __restrict__ out) {
  int tid = threadIdx.x;
  int row = blockIdx.x * 256 + tid;
  float ssum = 0.0f;
#pragma unroll
  for (int c = 0; c < COLG; ++c) ssum += slab[(size_t)c * N + row];
  float v = __logf(ssum - E_CONST) - pos[row];   // remove diag exp(sim_ii) ~= e
  for (int m = 1; m < 64; m <<= 1) v += __shfl_xor(v, m, 64);
  __shared__ float r4[4];
  if ((tid & 63) == 0) r4[tid >> 6] = v;
  __syncthreads();
  if (tid == 0)
    atomicAdd(out, (r4[0] + r4[1] + r4[2] + r4[3]) * (1.0f / (float)N));
}

extern "C" void kernel_launch(void* const* d_in, const int* in_sizes, int n_in,
                              void* d_out, int out_size, void* d_ws, size_t ws_size,
                              hipStream_t stream) {
  const float* feat = (const float*)d_in[0];
  unsigned char* f8 = (unsigned char*)d_ws;                                    // 2 MB
  float* pos  = (float*)((char*)d_ws + (size_t)N * D);                         // 32 KB
  float* slab = (float*)((char*)d_ws + (size_t)N * D + (size_t)N * 4);         // 1 MB
  float* out = (float*)d_out;

  norm_kernel<<<N / 4, 256, 0, stream>>>(feat, f8, pos, out);
  simlse_kernel<<<(N / RPB) * COLG, 512, 0, stream>>>(f8, slab);
  final_kernel<<<N / 256, 256, 0, stream>>>(slab, pos, out);
}